// Round 3
// baseline (764.613 us; speedup 1.0000x reference)
//
#include <hip/hip_runtime.h>
#include <cstdint>
#include <cstddef>

#define T_TOK 8192
#define C_DIM 2048
#define H_HEADS 8
#define D_HEAD 256

typedef __bf16 v8bf __attribute__((ext_vector_type(8)));
typedef float v4f __attribute__((ext_vector_type(4)));
typedef float v8f __attribute__((ext_vector_type(8)));

// Async global->LDS 16B copy. LDS dest semantics: wave-uniform base + lane*16.
__device__ __forceinline__ void async_load16(const void* gptr, void* lptr) {
    auto g = reinterpret_cast<__attribute__((address_space(1))) void*>(
        reinterpret_cast<uintptr_t>(gptr));
    auto l = reinterpret_cast<__attribute__((address_space(3))) void*>(
        static_cast<uint32_t>(reinterpret_cast<uintptr_t>(lptr)));
    __builtin_amdgcn_global_load_lds(g, l, 16, 0, 0);
}

// fp32 -> bf16, 8 elements per thread; n must be a multiple of 8*256.
__global__ __launch_bounds__(256) void cvt_kernel(
    const float* __restrict__ in, __bf16* __restrict__ out)
{
    const size_t i = ((size_t)blockIdx.x * 256 + threadIdx.x) * 8;
    v8f f = *(const v8f*)&in[i];
    v8bf b;
#pragma unroll
    for (int j = 0; j < 8; ++j) b[j] = (__bf16)f[j];
    *(v8bf*)&out[i] = b;
}

// C[m,n] = sum_k A[m,k]*B[n,k] + bias[n] (+ residual[m,n]); A,B bf16, fp32 accum.
// bias/residual fp32; output OutT (bf16 intermediate / fp32 final).
// A:[M,K], B:[N,K] row-major (A @ B^T). Block=256, tile 128x128, BK=32.
template <typename OutT>
__global__ __launch_bounds__(256) void gemm_bt_kernel(
    const __bf16* __restrict__ A, const __bf16* __restrict__ B,
    const float* __restrict__ bias, const float* __restrict__ residual,
    OutT* __restrict__ Cmat, int M, int N, int K)
{
    __shared__ __align__(16) __bf16 lds_a[128 * 32];  // [row][k], 64B rows, no pad
    __shared__ __align__(16) __bf16 lds_b[128 * 32];

    const int tid  = threadIdx.x;
    const int wave = tid >> 6;
    const int lane = tid & 63;
    const int block_m = blockIdx.y * 128;
    const int block_n = blockIdx.x * 128;
    const int wm = (wave >> 1) * 64;   // wave's 64x64 sub-tile
    const int wn = (wave & 1) * 64;

    const int lane_m = lane & 15;      // MFMA A/B row (m or n) within 16-tile
    const int quad   = lane >> 4;      // MFMA k-group: k = quad*8 + j

    v4f acc[4][4];
#pragma unroll
    for (int i = 0; i < 4; ++i)
#pragma unroll
        for (int j = 0; j < 4; ++j) {
            acc[i][j][0] = 0.f; acc[i][j][1] = 0.f;
            acc[i][j][2] = 0.f; acc[i][j][3] = 0.f;
        }

    for (int kt = 0; kt < K; kt += 32) {
        __syncthreads();  // previous iter's readers done before overwrite
#pragma unroll
        for (int q = 0; q < 2; ++q) {
            const int li  = q * 256 + wave * 64 + lane;  // 16B chunk id, 0..511
            const int row = li >> 2;                     // tile row 0..127
            const int kp  = li & 3;                      // 8-elem k sub-chunk
            const int ldsbase = (q * 256 + wave * 64) * 8;  // elems (wave-uniform)
            async_load16(&A[(size_t)(block_m + row) * K + kt + kp * 8], &lds_a[ldsbase]);
            async_load16(&B[(size_t)(block_n + row) * K + kt + kp * 8], &lds_b[ldsbase]);
        }
        __syncthreads();  // vmcnt(0) drain before barrier

        v8bf af[4], bfr[4];
#pragma unroll
        for (int i = 0; i < 4; ++i)
            af[i] = *(const v8bf*)&lds_a[(wm + i * 16 + lane_m) * 32 + quad * 8];
#pragma unroll
        for (int j = 0; j < 4; ++j)
            bfr[j] = *(const v8bf*)&lds_b[(wn + j * 16 + lane_m) * 32 + quad * 8];
#pragma unroll
        for (int i = 0; i < 4; ++i)
#pragma unroll
            for (int j = 0; j < 4; ++j)
                acc[i][j] = __builtin_amdgcn_mfma_f32_16x16x32_bf16(
                    af[i], bfr[j], acc[i][j], 0, 0, 0);
    }

    // Epilogue. C/D layout: col = lane&15, row = quad*4 + reg  [verified m89]
#pragma unroll
    for (int i = 0; i < 4; ++i) {
        const int row0 = block_m + wm + i * 16 + quad * 4;
#pragma unroll
        for (int j = 0; j < 4; ++j) {
            const int col = block_n + wn + j * 16 + lane_m;
            const float bv = bias[col];
#pragma unroll
            for (int r = 0; r < 4; ++r) {
                float val = acc[i][j][r] + bv;
                const size_t off = (size_t)(row0 + r) * N + col;
                if (residual) val += residual[off];
                Cmat[off] = (OutT)val;
            }
        }
    }
}

// Per-token 8x8 attention: one wave per token, 4 tokens per 256-thread block.
// out may alias q (q reads are value-dependencies of the stores).
__global__ __launch_bounds__(256) void attn_kernel(
    const __bf16* __restrict__ q, const __bf16* __restrict__ k,
    const __bf16* __restrict__ v, __bf16* __restrict__ out)
{
    __shared__ __align__(16) __bf16 sq[4 * 2048];
    __shared__ __align__(16) __bf16 sk[4 * 2048];
    __shared__ __align__(16) __bf16 sv[4 * 2048];

    const int wave = threadIdx.x >> 6;
    const int lane = threadIdx.x & 63;
    const int t = blockIdx.x * 4 + wave;

    const __bf16* qt = q + (size_t)t * C_DIM;
    const __bf16* kt = k + (size_t)t * C_DIM;
    const __bf16* vt = v + (size_t)t * C_DIM;
    __bf16* sqw = &sq[wave * C_DIM];
    __bf16* skw = &sk[wave * C_DIM];
    __bf16* svw = &sv[wave * C_DIM];

#pragma unroll
    for (int p = 0; p < 4; ++p) {
        const int idx = (p * 64 + lane) * 8;
        *(v8bf*)&sqw[idx] = *(const v8bf*)&qt[idx];
        *(v8bf*)&skw[idx] = *(const v8bf*)&kt[idx];
        *(v8bf*)&svw[idx] = *(const v8bf*)&vt[idx];
    }
    // all LDS traffic is wave-local: no __syncthreads needed

    // scores: lane owns (h = lane>>3, g = lane&7)
    const int h = lane >> 3;
    const int g = lane & 7;
    float s = 0.f;
#pragma unroll 4
    for (int d = 0; d < D_HEAD; d += 8) {
        v8bf qa = *(const v8bf*)&sqw[h * D_HEAD + d];
        v8bf ka = *(const v8bf*)&skw[g * D_HEAD + d];
#pragma unroll
        for (int jj = 0; jj < 8; ++jj) s += (float)qa[jj] * (float)ka[jj];
    }
    s *= 0.0625f;  // D^-0.5 = 1/16

    // softmax across g (8-lane groups; xor masks 1,2,4 stay in-group)
    float m = s;
    m = fmaxf(m, __shfl_xor(m, 1));
    m = fmaxf(m, __shfl_xor(m, 2));
    m = fmaxf(m, __shfl_xor(m, 4));
    const float e = __expf(s - m);
    float dsum = e;
    dsum += __shfl_xor(dsum, 1);
    dsum += __shfl_xor(dsum, 2);
    dsum += __shfl_xor(dsum, 4);
    const float p_attn = e / dsum;

    // PV: lane owns (head h, d-chunk = g*32..+32); gather attn row via shuffle
    float attnv[8];
#pragma unroll
    for (int gg = 0; gg < 8; ++gg)
        attnv[gg] = __shfl(p_attn, (lane & 56) | gg);

    __bf16* outp = out + (size_t)t * C_DIM + h * D_HEAD + g * 32;
    const __bf16* vbase = &svw[g * 32];
#pragma unroll
    for (int dd = 0; dd < 32; dd += 8) {
        float o[8] = {0.f, 0.f, 0.f, 0.f, 0.f, 0.f, 0.f, 0.f};
#pragma unroll
        for (int gg = 0; gg < 8; ++gg) {
            v8bf vv = *(const v8bf*)&vbase[gg * D_HEAD + dd];
            const float pg = attnv[gg];
#pragma unroll
            for (int jj = 0; jj < 8; ++jj) o[jj] += pg * (float)vv[jj];
        }
        v8bf ov;
#pragma unroll
        for (int jj = 0; jj < 8; ++jj) ov[jj] = (__bf16)o[jj];
        *(v8bf*)&outp[dd] = ov;
    }
}

extern "C" void kernel_launch(void* const* d_in, const int* in_sizes, int n_in,
                              void* d_out, int out_size, void* d_ws, size_t ws_size,
                              hipStream_t stream) {
    const float* x  = (const float*)d_in[0];
    const float* y  = (const float*)d_in[1];
    const float* Wq = (const float*)d_in[2];
    const float* bq = (const float*)d_in[3];
    const float* Wk = (const float*)d_in[4];
    const float* bk = (const float*)d_in[5];
    const float* Wv = (const float*)d_in[6];
    const float* bv = (const float*)d_in[7];
    const float* Wo = (const float*)d_in[8];
    const float* bo = (const float*)d_in[9];
    float* out = (float*)d_out;  // reference output dtype: fp32

    const size_t TC = (size_t)T_TOK * C_DIM;   // 16,777,216
    const size_t CC = (size_t)C_DIM * C_DIM;   //  4,194,304

    // workspace (bf16), 4*TC + CC elems = ~143 MB.
    // Single weight slot Wb reused sequentially (stream order serializes).
    // k reuses xb's slot after the Q-GEMM consumes xb.
    __bf16* xb   = (__bf16*)d_ws;
    __bf16* yb   = xb + TC;
    __bf16* q_ws = yb + TC;
    __bf16* v_ws = q_ws + TC;
    __bf16* Wb   = v_ws + TC;
    __bf16* k_ws = xb;      // safe: xb dead after Q-GEMM
    __bf16* a_ws = q_ws;    // attn overwrites q in place

    dim3 ggrid(C_DIM / 128, T_TOK / 128);
    dim3 gblock(256);
    const dim3 cvtTC(TC / (8 * 256)), cvtCC(CC / (8 * 256));

    cvt_kernel<<<cvtTC, gblock, 0, stream>>>(x, xb);
    cvt_kernel<<<cvtTC, gblock, 0, stream>>>(y, yb);

    cvt_kernel<<<cvtCC, gblock, 0, stream>>>(Wq, Wb);
    gemm_bt_kernel<__bf16><<<ggrid, gblock, 0, stream>>>(
        xb, Wb, bq, nullptr, q_ws, T_TOK, C_DIM, C_DIM);

    cvt_kernel<<<cvtCC, gblock, 0, stream>>>(Wk, Wb);
    gemm_bt_kernel<__bf16><<<ggrid, gblock, 0, stream>>>(
        yb, Wb, bk, nullptr, k_ws, T_TOK, C_DIM, C_DIM);

    cvt_kernel<<<cvtCC, gblock, 0, stream>>>(Wv, Wb);
    gemm_bt_kernel<__bf16><<<ggrid, gblock, 0, stream>>>(
        yb, Wb, bv, nullptr, v_ws, T_TOK, C_DIM, C_DIM);

    attn_kernel<<<dim3(T_TOK / 4), gblock, 0, stream>>>(q_ws, k_ws, v_ws, a_ws);

    cvt_kernel<<<cvtCC, gblock, 0, stream>>>(Wo, Wb);
    gemm_bt_kernel<float><<<ggrid, gblock, 0, stream>>>(
        a_ws, Wb, bo, x, out, T_TOK, C_DIM, C_DIM);
}

// Round 4
// 635.661 us; speedup vs baseline: 1.2029x; 1.2029x over previous
//
#include <hip/hip_runtime.h>
#include <cstdint>
#include <cstddef>

#define T_TOK 8192
#define C_DIM 2048
#define H_HEADS 8
#define D_HEAD 256

typedef __bf16 v8bf __attribute__((ext_vector_type(8)));
typedef float v4f __attribute__((ext_vector_type(4)));
typedef float v8f __attribute__((ext_vector_type(8)));

// Async global->LDS 16B copy. LDS dest semantics: wave-uniform base + lane*16.
__device__ __forceinline__ void async_load16(const void* gptr, void* lptr) {
    auto g = reinterpret_cast<__attribute__((address_space(1))) void*>(
        reinterpret_cast<uintptr_t>(gptr));
    auto l = reinterpret_cast<__attribute__((address_space(3))) void*>(
        static_cast<uint32_t>(reinterpret_cast<uintptr_t>(lptr)));
    __builtin_amdgcn_global_load_lds(g, l, 16, 0, 0);
}

// fp32 -> bf16, 8 elements per thread.
__global__ __launch_bounds__(256) void cvt_kernel(
    const float* __restrict__ in, __bf16* __restrict__ out)
{
    const size_t i = ((size_t)blockIdx.x * 256 + threadIdx.x) * 8;
    v8f f = *(const v8f*)&in[i];
    v8bf b;
#pragma unroll
    for (int j = 0; j < 8; ++j) b[j] = (__bf16)f[j];
    *(v8bf*)&out[i] = b;
}

// C[m,n] = sum_k A[m,k]*B[n,k] + bias[n] (+ residual[m,n]); A,B bf16, fp32 accum.
// 1-D grid, XCD-aware swizzle (same m-slab -> same XCD under id%8 round-robin).
// Tile 128x128, BK=64, swizzled LDS chunk order (global read rotated per row so
// fragment ds_read_b128 is 2-way-conflict max; global_load_lds dest stays
// lane-contiguous as required).
template <typename OutT>
__global__ __launch_bounds__(256) void gemm_bt_kernel(
    const __bf16* __restrict__ A, const __bf16* __restrict__ B,
    const float* __restrict__ bias, const float* __restrict__ residual,
    OutT* __restrict__ Cmat, int M, int N, int K)
{
    __shared__ __align__(16) __bf16 lds_a[128 * 64];  // 16 KB
    __shared__ __align__(16) __bf16 lds_b[128 * 64];  // 16 KB

    const int tid  = threadIdx.x;
    const int wave = tid >> 6;
    const int lane = tid & 63;

    // XCD swizzle: blocks sharing block_m land on one XCD (heuristic id%8).
    const int nbm = M >> 7;            // m-blocks (64)
    const int per_xcd_m = nbm >> 3;    // 8
    const int b = blockIdx.x;
    const int xcd = b & 7;
    const int slot = b >> 3;
    const int m_blk = xcd * per_xcd_m + (slot % per_xcd_m);
    const int n_blk = slot / per_xcd_m;
    const int block_m = m_blk * 128;
    const int block_n = n_blk * 128;

    const int wm = (wave >> 1) * 64;   // wave's 64x64 sub-tile
    const int wn = (wave & 1) * 64;
    const int lane_m = lane & 15;      // MFMA A/B m/n within 16-tile
    const int quad   = lane >> 4;      // MFMA k-group: k = quad*8 + j

    v4f acc[4][4];
#pragma unroll
    for (int i = 0; i < 4; ++i)
#pragma unroll
        for (int j = 0; j < 4; ++j) {
            acc[i][j][0] = 0.f; acc[i][j][1] = 0.f;
            acc[i][j][2] = 0.f; acc[i][j][3] = 0.f;
        }

    for (int kt = 0; kt < K; kt += 64) {
        __syncthreads();  // previous iter's readers done before overwrite
#pragma unroll
        for (int q = 0; q < 4; ++q) {
            const int li  = q * 256 + wave * 64 + lane;  // 16B chunk id, 0..1023
            const int row = li >> 3;                     // tile row 0..127
            const int p   = li & 7;                      // LDS chunk slot in row
            const int c   = (p - row) & 7;               // rotated global chunk
            const int ldsbase = (q * 256 + wave * 64) * 8;  // elems (wave-uniform)
            async_load16(&A[(size_t)(block_m + row) * K + kt + c * 8], &lds_a[ldsbase]);
            async_load16(&B[(size_t)(block_n + row) * K + kt + c * 8], &lds_b[ldsbase]);
        }
        __syncthreads();  // vmcnt(0) drain before barrier

#pragma unroll
        for (int kk = 0; kk < 2; ++kk) {
            v8bf af[4], bfr[4];
#pragma unroll
            for (int i = 0; i < 4; ++i) {
                const int r = wm + i * 16 + lane_m;
                const int p = (kk * 4 + quad + r) & 7;   // inverse swizzle
                af[i] = *(const v8bf*)&lds_a[r * 64 + p * 8];
            }
#pragma unroll
            for (int j = 0; j < 4; ++j) {
                const int r = wn + j * 16 + lane_m;
                const int p = (kk * 4 + quad + r) & 7;
                bfr[j] = *(const v8bf*)&lds_b[r * 64 + p * 8];
            }
#pragma unroll
            for (int i = 0; i < 4; ++i)
#pragma unroll
                for (int j = 0; j < 4; ++j)
                    acc[i][j] = __builtin_amdgcn_mfma_f32_16x16x32_bf16(
                        af[i], bfr[j], acc[i][j], 0, 0, 0);
        }
    }

    // Epilogue. C/D layout: col = lane&15, row = quad*4 + reg  [verified m89]
#pragma unroll
    for (int i = 0; i < 4; ++i) {
        const int row0 = block_m + wm + i * 16 + quad * 4;
#pragma unroll
        for (int j = 0; j < 4; ++j) {
            const int col = block_n + wn + j * 16 + lane_m;
            const float bv = bias[col];
#pragma unroll
            for (int r = 0; r < 4; ++r) {
                float val = acc[i][j][r] + bv;
                const size_t off = (size_t)(row0 + r) * N + col;
                if (residual) val += residual[off];
                Cmat[off] = (OutT)val;
            }
        }
    }
}

// Per-token 8x8 attention: one wave per token, 4 tokens per 256-thread block.
// q/out stride 2048; k,v packed in kv with token stride 4096 (k at +0, v at +2048).
// out may alias q (q reads are value-dependencies of the stores).
__global__ __launch_bounds__(256) void attn_kernel(
    const __bf16* __restrict__ q, const __bf16* __restrict__ kv,
    __bf16* __restrict__ out)
{
    __shared__ __align__(16) __bf16 sq[4 * 2048];
    __shared__ __align__(16) __bf16 sk[4 * 2048];
    __shared__ __align__(16) __bf16 sv[4 * 2048];

    const int wave = threadIdx.x >> 6;
    const int lane = threadIdx.x & 63;
    const int t = blockIdx.x * 4 + wave;

    const __bf16* qt = q + (size_t)t * C_DIM;
    const __bf16* kt = kv + (size_t)t * 2 * C_DIM;
    const __bf16* vt = kt + C_DIM;
    __bf16* sqw = &sq[wave * C_DIM];
    __bf16* skw = &sk[wave * C_DIM];
    __bf16* svw = &sv[wave * C_DIM];

#pragma unroll
    for (int p = 0; p < 4; ++p) {
        const int idx = (p * 64 + lane) * 8;
        *(v8bf*)&sqw[idx] = *(const v8bf*)&qt[idx];
        *(v8bf*)&skw[idx] = *(const v8bf*)&kt[idx];
        *(v8bf*)&svw[idx] = *(const v8bf*)&vt[idx];
    }
    // all LDS traffic is wave-local: no __syncthreads needed

    const int h = lane >> 3;
    const int g = lane & 7;
    float s = 0.f;
#pragma unroll 4
    for (int d = 0; d < D_HEAD; d += 8) {
        v8bf qa = *(const v8bf*)&sqw[h * D_HEAD + d];
        v8bf ka = *(const v8bf*)&skw[g * D_HEAD + d];
#pragma unroll
        for (int jj = 0; jj < 8; ++jj) s += (float)qa[jj] * (float)ka[jj];
    }
    s *= 0.0625f;  // D^-0.5 = 1/16

    float m = s;
    m = fmaxf(m, __shfl_xor(m, 1));
    m = fmaxf(m, __shfl_xor(m, 2));
    m = fmaxf(m, __shfl_xor(m, 4));
    const float e = __expf(s - m);
    float dsum = e;
    dsum += __shfl_xor(dsum, 1);
    dsum += __shfl_xor(dsum, 2);
    dsum += __shfl_xor(dsum, 4);
    const float p_attn = e / dsum;

    float attnv[8];
#pragma unroll
    for (int gg = 0; gg < 8; ++gg)
        attnv[gg] = __shfl(p_attn, (lane & 56) | gg);

    __bf16* outp = out + (size_t)t * C_DIM + h * D_HEAD + g * 32;
    const __bf16* vbase = &svw[g * 32];
#pragma unroll
    for (int dd = 0; dd < 32; dd += 8) {
        float o[8] = {0.f, 0.f, 0.f, 0.f, 0.f, 0.f, 0.f, 0.f};
#pragma unroll
        for (int gg = 0; gg < 8; ++gg) {
            v8bf vv = *(const v8bf*)&vbase[gg * D_HEAD + dd];
            const float pg = attnv[gg];
#pragma unroll
            for (int jj = 0; jj < 8; ++jj) o[jj] += pg * (float)vv[jj];
        }
        v8bf ov;
#pragma unroll
        for (int jj = 0; jj < 8; ++jj) ov[jj] = (__bf16)o[jj];
        *(v8bf*)&outp[dd] = ov;
    }
}

extern "C" void kernel_launch(void* const* d_in, const int* in_sizes, int n_in,
                              void* d_out, int out_size, void* d_ws, size_t ws_size,
                              hipStream_t stream) {
    const float* x  = (const float*)d_in[0];
    const float* y  = (const float*)d_in[1];
    const float* Wq = (const float*)d_in[2];
    const float* bq = (const float*)d_in[3];
    const float* Wk = (const float*)d_in[4];
    const float* bk = (const float*)d_in[5];
    const float* Wv = (const float*)d_in[6];
    const float* bv = (const float*)d_in[7];
    const float* Wo = (const float*)d_in[8];
    const float* bo = (const float*)d_in[9];
    float* out = (float*)d_out;  // fp32 output

    const size_t TC = (size_t)T_TOK * C_DIM;   // 16,777,216
    const size_t CC = (size_t)C_DIM * C_DIM;   //  4,194,304

    // bf16 workspace, 4*TC + 2*CC elems (~151 MB) + 16 KB fp32 bias:
    //   [xb TC][ext TC][yb TC][q TC][Wb 2CC][bias_kv 4096 f32]
    // kv_ws overlays xb+ext (xb dead after Q-GEMM; stream order serializes).
    __bf16* xb    = (__bf16*)d_ws;
    __bf16* kv_ws = xb;                 // 2*TC, written after xb is dead
    __bf16* yb    = xb + 2 * TC;
    __bf16* q_ws  = yb + TC;
    __bf16* Wb    = q_ws + TC;          // 2*CC slot, reused sequentially
    float*  bias_kv = (float*)(Wb + 2 * CC);
    __bf16* a_ws  = q_ws;               // attn overwrites q in place

    dim3 gblock(256);
    const dim3 cvtTC(TC / (8 * 256)), cvtCC(CC / (8 * 256));

    cvt_kernel<<<cvtTC, gblock, 0, stream>>>(x, xb);
    cvt_kernel<<<cvtTC, gblock, 0, stream>>>(y, yb);
    hipMemcpyAsync(bias_kv,        bk, C_DIM * sizeof(float),
                   hipMemcpyDeviceToDevice, stream);
    hipMemcpyAsync(bias_kv + C_DIM, bv, C_DIM * sizeof(float),
                   hipMemcpyDeviceToDevice, stream);

    // Q = x @ Wq^T + bq
    cvt_kernel<<<cvtCC, gblock, 0, stream>>>(Wq, Wb);
    gemm_bt_kernel<__bf16><<<dim3((T_TOK/128)*(C_DIM/128)), gblock, 0, stream>>>(
        xb, Wb, bq, nullptr, q_ws, T_TOK, C_DIM, C_DIM);

    // [K|V] = y @ [Wk;Wv]^T + [bk;bv]   (N = 4096, overlays xb+ext)
    cvt_kernel<<<cvtCC, gblock, 0, stream>>>(Wk, Wb);
    cvt_kernel<<<cvtCC, gblock, 0, stream>>>(Wv, Wb + CC);
    gemm_bt_kernel<__bf16><<<dim3((T_TOK/128)*(2*C_DIM/128)), gblock, 0, stream>>>(
        yb, Wb, bias_kv, nullptr, kv_ws, T_TOK, 2 * C_DIM, C_DIM);

    attn_kernel<<<dim3(T_TOK / 4), gblock, 0, stream>>>(q_ws, kv_ws, a_ws);

    // out = attn @ Wo^T + bo + x
    cvt_kernel<<<cvtCC, gblock, 0, stream>>>(Wo, Wb);
    gemm_bt_kernel<float><<<dim3((T_TOK/128)*(C_DIM/128)), gblock, 0, stream>>>(
        a_ws, Wb, bo, x, out, T_TOK, C_DIM, C_DIM);
}